// Round 3
// baseline (239.563 us; speedup 1.0000x reference)
//
#include <hip/hip_runtime.h>
#include <hip/hip_bf16.h>

#define N_Q   16384
#define MCTX  4096
#define DSIN  256
#define YDIM  7
#define PDIM  256   // SPROJ
#define BK    32
#define PSTR  40    // Pe/Pr leading stride in u16 (80B: b128-aligned, conflict-free)

typedef __attribute__((ext_vector_type(8))) short s16x8;   // 8 bf16 (4 VGPRs)
typedef __attribute__((ext_vector_type(4))) float f32x4;   // MFMA C/D frag
typedef unsigned short u16;

static __device__ __forceinline__ u16 f2bf(float f) {
    union { float f; unsigned u; } v; v.f = f;
    unsigned r = v.u + 0x7fffu + ((v.u >> 16) & 1u);  // RNE
    return (u16)(r >> 16);
}
static __device__ __forceinline__ float bf2f(u16 h) {
    union { unsigned u; float f; } v; v.u = ((unsigned)h) << 16;
    return v.f;
}
static __device__ __forceinline__ f32x4 mfma16(s16x8 a, s16x8 b, f32x4 c) {
    return __builtin_amdgcn_mfma_f32_16x16x32_bf16(a, b, c, 0, 0, 0);
}
// async 16B global->LDS DMA (dst = wave-uniform base + lane*16)
static __device__ __forceinline__ void gload_lds16(const u16* g, u16* l) {
    __builtin_amdgcn_global_load_lds(
        (const __attribute__((address_space(1))) unsigned int*)(g),
        (__attribute__((address_space(3))) unsigned int*)(l), 16, 0, 0);
}

// ---------------- K0: Wq transpose + hi/lo bf16 split ----------------
__global__ void k_wt(const float* __restrict__ Wq, u16* __restrict__ WtH,
                     u16* __restrict__ WtL) {
    int n = blockIdx.x;   // 0..PDIM-1
    int k = threadIdx.x;  // 0..DSIN-1
    float w = Wq[(size_t)k * PDIM + n];
    u16 h = f2bf(w);
    WtH[(size_t)n * DSIN + k] = h;
    WtL[(size_t)n * DSIN + k] = f2bf(w - bf2f(h));
}

// ---------------- K2: YK (scaled 1/16) + YVb (pi-interleaved PV-frag layout) ----
// pi(key&31) = 2*(key&15) + (key>>4): YVb[kb][p][pi] so P/V k-orders match.
// Thread (p, quarter) computes the 8 keys whose pi-slots are quarter*8..+7,
// storing one contiguous 16B run.
__global__ void k_ykv(const float* __restrict__ y, const float* __restrict__ Wk,
                      const float* __restrict__ Wv, u16* __restrict__ YK,
                      u16* __restrict__ YVb) {
    int kb = blockIdx.x;                 // 32-key block
    int p  = threadIdx.x & 255;
    int quarter = threadIdx.x >> 8;      // 0..3
    float wk[YDIM], wv[YDIM];
#pragma unroll
    for (int j = 0; j < YDIM; ++j) {
        wk[j] = Wk[(size_t)j * PDIM + p];
        wv[j] = Wv[(size_t)j * PDIM + p];
    }
    s16x8 vbuf;
#pragma unroll
    for (int i = 0; i < 8; ++i) {
        int slot = quarter * 8 + i;
        int m = (slot & 1) * 16 + (slot >> 1);   // pi^-1(slot)
        int key = kb * 32 + m;
        float ak = 0.f, av = 0.f;
#pragma unroll
        for (int j = 0; j < YDIM; ++j) {
            float yy = y[(size_t)key * YDIM + j];
            ak += yy * wk[j];
            av += yy * wv[j];
        }
        YK[(size_t)key * PDIM + p] = f2bf(ak * 0.0625f);  // fold 1/sqrt(256)
        vbuf[i] = (short)f2bf(av);
    }
    *(s16x8*)(YVb + ((size_t)kb * PDIM + p) * 32 + quarter * 8) = vbuf;
}

// ---------------- K1: XQ = x @ Wq, hi/lo split; 32-row blocks for occupancy ----
__global__ __launch_bounds__(256, 4) void k_xq(const float* __restrict__ x,
                                               const u16* __restrict__ WtH,
                                               const u16* __restrict__ WtL,
                                               u16* __restrict__ XQ) {
    __shared__ u16 xH[32 * 256];  // XOR-swizzled 16B chunks: phys c = c ^ (row&7)
    __shared__ u16 xL[32 * 256];
    const int tid = threadIdx.x;
    const int rowg0 = blockIdx.x * 32;

#pragma unroll
    for (int i = 0; i < 4; ++i) {
        int idx = i * 256 + tid;
        int row = idx >> 5, c32 = idx & 31;
        const float* px = x + (size_t)(rowg0 + row) * DSIN + c32 * 8;
        float4 a = *(const float4*)px;
        float4 b = *(const float4*)(px + 4);
        float vals[8] = {a.x, a.y, a.z, a.w, b.x, b.y, b.z, b.w};
        s16x8 h, l;
#pragma unroll
        for (int j = 0; j < 8; ++j) {
            u16 hh = f2bf(vals[j]);
            h[j] = (short)hh;
            l[j] = (short)f2bf(vals[j] - bf2f(hh));
        }
        int pc = c32 ^ (row & 7);
        *(s16x8*)(xH + row * 256 + pc * 8) = h;
        *(s16x8*)(xL + row * 256 + pc * 8) = l;
    }
    __syncthreads();

    const int wave = tid >> 6, lane = tid & 63;
    const int quad = lane >> 4, m16 = lane & 15;
    const int mtile = wave >> 1;          // 0..1 (16-row tile)
    const int phalf = (wave & 1) * 8;     // pt range
    const int rowl = mtile * 16 + m16;
    const int swz = rowl & 7;
    s16x8 ah[8], al[8];
#pragma unroll
    for (int kf = 0; kf < 8; ++kf) {
        int pc = (kf * 4 + quad) ^ swz;
        ah[kf] = *(const s16x8*)(xH + rowl * 256 + pc * 8);
        al[kf] = *(const s16x8*)(xL + rowl * 256 + pc * 8);
    }
#pragma unroll
    for (int pt = 0; pt < 8; ++pt) {
        int ptg = phalf + pt;
        f32x4 acc = (f32x4){0.f, 0.f, 0.f, 0.f};
#pragma unroll
        for (int kf = 0; kf < 8; ++kf) {
            size_t idx = (size_t)(ptg * 16 + m16) * DSIN + kf * 32 + quad * 8;
            s16x8 bh = *(const s16x8*)(WtH + idx);
            s16x8 bl = *(const s16x8*)(WtL + idx);
            acc = mfma16(ah[kf], bh, acc);
            acc = mfma16(al[kf], bh, acc);
            acc = mfma16(ah[kf], bl, acc);
        }
#pragma unroll
        for (int r = 0; r < 4; ++r)
            XQ[(size_t)(rowg0 + mtile * 16 + quad * 4 + r) * PDIM + ptg * 16 + m16] =
                f2bf(acc[r]);
    }
}

// ---------------- K3: fused attention, cooperative-S, pi-packed P ----------------
__global__ __launch_bounds__(256, 2) void k_attn(const u16* __restrict__ XQ,
                                                 const u16* __restrict__ YK,
                                                 const u16* __restrict__ YVb,
                                                 u16* __restrict__ accE,
                                                 u16* __restrict__ accR,
                                                 float* __restrict__ lsum,
                                                 float* __restrict__ rsum,
                                                 int msPerSplit) {
    __shared__ u16 Kt[32 * 256];       // 32 keys x 256 d, XOR-swizzled chunks
    __shared__ u16 Pe[64 * PSTR];      // 64 q x 32 key-slots (pi order)
    __shared__ u16 Pr[64 * PSTR];

    const int tid = threadIdx.x;
    const int wave = tid >> 6, lane = tid & 63;
    const int quad = lane >> 4, m16 = lane & 15;
    const int split = blockIdx.y;
    const int qbase = blockIdx.x * 64;
    const int key_begin = split * msPerSplit;
    const int iters = msPerSplit / BK;
    const int pslice = wave * 64;
    const int swz = m16 & 7;

    // Q A-frags for this wave's 16 S-rows
    s16x8 qf[8];
    const u16* qp = XQ + (size_t)(qbase + wave * 16 + m16) * DSIN;
#pragma unroll
    for (int kf = 0; kf < 8; ++kf)
        qf[kf] = *(const s16x8*)(qp + kf * 32 + quad * 8);

    f32x4 aE[4][4], aR[4][4];
#pragma unroll
    for (int g = 0; g < 4; ++g)
#pragma unroll
        for (int t = 0; t < 4; ++t) {
            aE[g][t] = (f32x4){0.f, 0.f, 0.f, 0.f};
            aR[g][t] = (f32x4){0.f, 0.f, 0.f, 0.f};
        }
    float lacc[4] = {0.f, 0.f, 0.f, 0.f}, racc[4] = {0.f, 0.f, 0.f, 0.f};

    auto stage = [&](int key0) {
#pragma unroll
        for (int c = 0; c < 4; ++c) {
            int l = (wave * 4 + c) * 64 + lane;   // phys chunk 0..1023
            int r = l >> 5;                        // key row 0..31
            int sc = (l & 31) ^ (r & 7);           // source chunk in row
            gload_lds16(YK + (size_t)(key0 + r) * DSIN + sc * 8,
                        Kt + (size_t)(wave * 4 + c) * 512);
        }
    };
    stage(key_begin);

    for (int it = 0; it < iters; ++it) {
        const int key0 = key_begin + it * BK;
        __syncthreads();   // Kt(it) visible (vmcnt0 + barrier)

        // QK: S rows wave*16+quad*4+r, keys m16 (s0) and 16+m16 (s1)
        f32x4 s0 = (f32x4){0.f, 0.f, 0.f, 0.f};
        f32x4 s1 = (f32x4){0.f, 0.f, 0.f, 0.f};
#pragma unroll
        for (int kf = 0; kf < 8; ++kf) {
            int pc = (kf * 4 + quad) ^ swz;        // (16+m16)&7 == m16&7
            s16x8 b0 = *(const s16x8*)(Kt + m16 * 256 + pc * 8);
            s16x8 b1 = *(const s16x8*)(Kt + (16 + m16) * 256 + pc * 8);
            s0 = mfma16(qf[kf], b0, s0);
            s1 = mfma16(qf[kf], b1, s1);
        }
        // exp/relu; pack (key m16, key 16+m16) -> pi slots (2*m16, 2*m16+1) = one b32
#pragma unroll
        for (int r = 0; r < 4; ++r) {
            float e0 = __expf(s0[r]), e1 = __expf(s1[r]);
            float rl0 = fmaxf(s0[r], 0.f), rl1 = fmaxf(s1[r], 0.f);
            lacc[r] += e0 + e1;
            racc[r] += rl0 + rl1;
            int row = wave * 16 + quad * 4 + r;
            unsigned pe = (unsigned)f2bf(e0) | ((unsigned)f2bf(e1) << 16);
            unsigned pr = (unsigned)f2bf(rl0) | ((unsigned)f2bf(rl1) << 16);
            *(unsigned*)(&Pe[row * PSTR + 2 * m16]) = pe;
            *(unsigned*)(&Pr[row * PSTR + 2 * m16]) = pr;
        }
        __syncthreads();   // Pe/Pr visible; Kt free to overwrite

        // V-frags first (so their vmcnt wait doesn't drain the DMA below)
        s16x8 vf[4];
        const u16* vb = YVb + (size_t)((key0 >> 5) * PDIM) * 32;
#pragma unroll
        for (int t = 0; t < 4; ++t)
            vf[t] = *(const s16x8*)(vb + (size_t)(pslice + t * 16 + m16) * 32 + quad * 8);

        if (it + 1 < iters) stage(key0 + BK);  // async prefetch of next K tile

        // PV: dual path; A-frag k-slice = pi slots quad*8..+7, matching YVb order
#pragma unroll
        for (int g = 0; g < 4; ++g) {
            s16x8 pa = *(const s16x8*)(&Pe[(g * 16 + m16) * PSTR + quad * 8]);
            s16x8 pb = *(const s16x8*)(&Pr[(g * 16 + m16) * PSTR + quad * 8]);
#pragma unroll
            for (int t = 0; t < 4; ++t) {
                aE[g][t] = mfma16(pa, vf[t], aE[g][t]);
                aR[g][t] = mfma16(pb, vf[t], aR[g][t]);
            }
        }
    }

    // epilogue: bf16 partial O and fp32 row sums
    size_t ob = ((size_t)split * N_Q + qbase) * PDIM;
#pragma unroll
    for (int g = 0; g < 4; ++g)
#pragma unroll
        for (int t = 0; t < 4; ++t)
#pragma unroll
            for (int r = 0; r < 4; ++r) {
                size_t o = ob + (size_t)(g * 16 + quad * 4 + r) * PDIM + pslice + t * 16 + m16;
                accE[o] = f2bf(aE[g][t][r]);
                accR[o] = f2bf(aR[g][t][r]);
            }
#pragma unroll
    for (int r = 0; r < 4; ++r) {
        lacc[r] += __shfl_xor(lacc[r], 1);
        lacc[r] += __shfl_xor(lacc[r], 2);
        lacc[r] += __shfl_xor(lacc[r], 4);
        lacc[r] += __shfl_xor(lacc[r], 8);
        racc[r] += __shfl_xor(racc[r], 1);
        racc[r] += __shfl_xor(racc[r], 2);
        racc[r] += __shfl_xor(racc[r], 4);
        racc[r] += __shfl_xor(racc[r], 8);
    }
    if (m16 < 4) {
        float lv = (m16 == 0) ? lacc[0] : (m16 == 1) ? lacc[1] : (m16 == 2) ? lacc[2] : lacc[3];
        float rv = (m16 == 0) ? racc[0] : (m16 == 1) ? racc[1] : (m16 == 2) ? racc[2] : racc[3];
        int row = split * N_Q + qbase + wave * 16 + quad * 4 + m16;
        lsum[row] = lv;
        rsum[row] = rv;
    }
}

// ---------------- K4: combine bf16 partials + normalization ----------------
__global__ void k_comb(const u16* __restrict__ accE, const u16* __restrict__ accR,
                       const float* __restrict__ lsum, const float* __restrict__ rsum,
                       float* __restrict__ out, int nsplit) {
    size_t chunk = (size_t)blockIdx.x * 256 + threadIdx.x;  // 8 cols per thread
    int row = (int)(chunk >> 5);
    size_t base = (size_t)row * PDIM + (chunk & 31) * 8;
    const size_t NP = (size_t)N_Q * PDIM;
    float E[8], R[8];
#pragma unroll
    for (int j = 0; j < 8; ++j) { E[j] = 0.f; R[j] = 0.f; }
    float L = 0.f, Rs = 0.f;
    for (int s = 0; s < nsplit; ++s) {
        s16x8 e = *(const s16x8*)(accE + s * NP + base);
        s16x8 r = *(const s16x8*)(accR + s * NP + base);
#pragma unroll
        for (int j = 0; j < 8; ++j) {
            E[j] += bf2f((u16)e[j]);
            R[j] += bf2f((u16)r[j]);
        }
        L  += lsum[(size_t)s * N_Q + row];
        Rs += rsum[(size_t)s * N_Q + row];
    }
    float invL = 1.f / L, invD = 1.f / (1.f + 0.1f * Rs);
    float4 o0, o1;
    o0.x = (0.1f * R[0] + E[0] * invL) * invD;
    o0.y = (0.1f * R[1] + E[1] * invL) * invD;
    o0.z = (0.1f * R[2] + E[2] * invL) * invD;
    o0.w = (0.1f * R[3] + E[3] * invL) * invD;
    o1.x = (0.1f * R[4] + E[4] * invL) * invD;
    o1.y = (0.1f * R[5] + E[5] * invL) * invD;
    o1.z = (0.1f * R[6] + E[6] * invL) * invD;
    o1.w = (0.1f * R[7] + E[7] * invL) * invD;
    *(float4*)(out + base) = o0;
    *(float4*)(out + base + 4) = o1;
}

extern "C" void kernel_launch(void* const* d_in, const int* in_sizes, int n_in,
                              void* d_out, int out_size, void* d_ws, size_t ws_size,
                              hipStream_t stream) {
    const float* x  = (const float*)d_in[0];
    const float* y  = (const float*)d_in[1];
    const float* Wq = (const float*)d_in[2];
    const float* Wk = (const float*)d_in[3];
    const float* Wv = (const float*)d_in[4];
    float* out = (float*)d_out;

    char* ws = (char*)d_ws;
    size_t off = 0;
    auto take = [&](size_t bytes) -> char* {
        char* p = ws + off;
        off += (bytes + 255) & ~(size_t)255;
        return p;
    };
    u16* XQ  = (u16*)take((size_t)N_Q * PDIM * 2);
    u16* WtH = (u16*)take((size_t)PDIM * DSIN * 2);
    u16* WtL = (u16*)take((size_t)PDIM * DSIN * 2);
    u16* YK  = (u16*)take((size_t)MCTX * PDIM * 2);
    u16* YVb = (u16*)take((size_t)MCTX * PDIM * 2);

    // bf16 partials: per split = accE+accR (2*N*P*2B) + lsum+rsum (2*N*4B)
    size_t perSplit = (size_t)N_Q * PDIM * 2 * 2 + (size_t)N_Q * 4 * 2 + 1024;
    int nsplit = 1;
    if (ws_size >= off + 4 * perSplit + 4096) nsplit = 4;
    else if (ws_size >= off + 2 * perSplit + 4096) nsplit = 2;

    u16*   accE = (u16*)take((size_t)nsplit * N_Q * PDIM * 2);
    u16*   accR = (u16*)take((size_t)nsplit * N_Q * PDIM * 2);
    float* lsum = (float*)take((size_t)nsplit * N_Q * 4);
    float* rsum = (float*)take((size_t)nsplit * N_Q * 4);

    hipLaunchKernelGGL(k_wt,   dim3(PDIM),     dim3(DSIN), 0, stream, Wq, WtH, WtL);
    hipLaunchKernelGGL(k_ykv,  dim3(MCTX/32),  dim3(1024), 0, stream, y, Wk, Wv, YK, YVb);
    hipLaunchKernelGGL(k_xq,   dim3(N_Q/32),   dim3(256),  0, stream, x, WtH, WtL, XQ);
    hipLaunchKernelGGL(k_attn, dim3(N_Q/64, nsplit), dim3(256), 0, stream,
                       XQ, YK, YVb, accE, accR, lsum, rsum, MCTX / nsplit);
    hipLaunchKernelGGL(k_comb, dim3((N_Q * PDIM) / (256 * 8)), dim3(256), 0, stream,
                       accE, accR, lsum, rsum, out, nsplit);
}

// Round 5
// 239.177 us; speedup vs baseline: 1.0016x; 1.0016x over previous
//
#include <hip/hip_runtime.h>
#include <hip/hip_bf16.h>

#define N_Q   16384
#define MCTX  4096
#define DSIN  256
#define YDIM  7
#define PDIM  256   // SPROJ
#define BK    32
#define PSTRB 40    // Pe/Pr row stride in BYTES (32 fp8 slots + 8 pad)

typedef __attribute__((ext_vector_type(8))) short s16x8;   // 8 bf16 (4 VGPRs)
typedef __attribute__((ext_vector_type(4))) float f32x4;   // MFMA C/D frag
typedef unsigned short u16;
typedef unsigned char  u8;
typedef long long      i64;
typedef unsigned long long u64;

static __device__ __forceinline__ u16 f2bf(float f) {
    union { float f; unsigned u; } v; v.f = f;
    unsigned r = v.u + 0x7fffu + ((v.u >> 16) & 1u);  // RNE
    return (u16)(r >> 16);
}
static __device__ __forceinline__ float bf2f(u16 h) {
    union { unsigned u; float f; } v; v.u = ((unsigned)h) << 16;
    return v.f;
}
static __device__ __forceinline__ f32x4 mfma_bf16(s16x8 a, s16x8 b, f32x4 c) {
    return __builtin_amdgcn_mfma_f32_16x16x32_bf16(a, b, c, 0, 0, 0);
}
static __device__ __forceinline__ f32x4 mfma_fp8(i64 a, i64 b, f32x4 c) {
    return __builtin_amdgcn_mfma_f32_16x16x32_fp8_fp8(a, b, c, 0, 0, 0);
}
// 2 floats -> 2 OCP e4m3 bytes (low 16 bits)
static __device__ __forceinline__ unsigned cvt2fp8(float a, float b) {
    return (unsigned)__builtin_amdgcn_cvt_pk_fp8_f32(a, b, 0, false) & 0xffffu;
}
// 8 floats -> 8 fp8 bytes
static __device__ __forceinline__ i64 pack_fp8x8(const float* v) {
    unsigned w0 = (unsigned)__builtin_amdgcn_cvt_pk_fp8_f32(v[0], v[1], 0, false);
    w0 = (unsigned)__builtin_amdgcn_cvt_pk_fp8_f32(v[2], v[3], (int)w0, true);
    unsigned w1 = (unsigned)__builtin_amdgcn_cvt_pk_fp8_f32(v[4], v[5], 0, false);
    w1 = (unsigned)__builtin_amdgcn_cvt_pk_fp8_f32(v[6], v[7], (int)w1, true);
    return (i64)(((u64)w1 << 32) | w0);
}
// exact e4m3fn -> f32 decode (no NaN inputs here)
static __device__ __forceinline__ float fp8dec(unsigned b) {
    unsigned s = b >> 7, e = (b >> 3) & 15, m = b & 7;
    if (e == 0) return (s ? -1.f : 1.f) * (float)m * 0.001953125f;  // m * 2^-9
    union { unsigned u; float f; } v;
    v.u = (s << 31) | ((e + 120u) << 23) | (m << 20);  // bias 7 -> 127
    return v.f;
}
// async 16B global->LDS DMA (dst = wave-uniform base + lane*16)
static __device__ __forceinline__ void gload_lds16(const void* g, void* l) {
    __builtin_amdgcn_global_load_lds(
        (const __attribute__((address_space(1))) unsigned int*)(g),
        (__attribute__((address_space(3))) unsigned int*)(l), 16, 0, 0);
}

// ---------------- K0: Wq transpose + hi/lo bf16 split ----------------
__global__ void k_wt(const float* __restrict__ Wq, u16* __restrict__ WtH,
                     u16* __restrict__ WtL) {
    int n = blockIdx.x;   // 0..PDIM-1
    int k = threadIdx.x;  // 0..DSIN-1
    float w = Wq[(size_t)k * PDIM + n];
    u16 h = f2bf(w);
    WtH[(size_t)n * DSIN + k] = h;
    WtL[(size_t)n * DSIN + k] = f2bf(w - bf2f(h));
}

// ---------------- K2: YK8 fp8 (x0.25) row-major + YVb8 fp8 pi-layout ----------
// pi(m) = 2*(m&15)+(m>>4). Thread (p, quarter) handles pi-slots quarter*8..+7.
__global__ void k_ykv(const float* __restrict__ y, const float* __restrict__ Wk,
                      const float* __restrict__ Wv, u8* __restrict__ YK8,
                      u8* __restrict__ YVb8) {
    int kb = blockIdx.x;                 // 32-key block
    int p  = threadIdx.x & 255;
    int quarter = threadIdx.x >> 8;      // 0..3
    float wk[YDIM], wv[YDIM];
#pragma unroll
    for (int j = 0; j < YDIM; ++j) {
        wk[j] = Wk[(size_t)j * PDIM + p];
        wv[j] = Wv[(size_t)j * PDIM + p];
    }
    float vv[8];
#pragma unroll
    for (int i = 0; i < 8; ++i) {
        int slot = quarter * 8 + i;
        int m = (slot & 1) * 16 + (slot >> 1);   // pi^-1(slot)
        int key = kb * 32 + m;
        float ak = 0.f, av = 0.f;
#pragma unroll
        for (int j = 0; j < YDIM; ++j) {
            float yy = y[(size_t)key * YDIM + j];
            ak += yy * wk[j];
            av += yy * wv[j];
        }
        YK8[(size_t)key * PDIM + p] = (u8)(cvt2fp8(ak * 0.25f, 0.f) & 0xff);
        vv[i] = av;
    }
    *(i64*)(YVb8 + ((size_t)kb * PDIM + p) * 32 + quarter * 8) = pack_fp8x8(vv);
}

// ---------------- K1: XQ = x @ Wq via hi/lo bf16 split, fp32 output ----------
__global__ __launch_bounds__(256, 4) void k_xq(const float* __restrict__ x,
                                               const u16* __restrict__ WtH,
                                               const u16* __restrict__ WtL,
                                               float* __restrict__ XQ) {
    __shared__ u16 xH[32 * 256];  // XOR-swizzled 16B chunks: phys c = c ^ (row&7)
    __shared__ u16 xL[32 * 256];
    const int tid = threadIdx.x;
    const int rowg0 = blockIdx.x * 32;

#pragma unroll
    for (int i = 0; i < 4; ++i) {
        int idx = i * 256 + tid;
        int row = idx >> 5, c32 = idx & 31;
        const float* px = x + (size_t)(rowg0 + row) * DSIN + c32 * 8;
        float4 a = *(const float4*)px;
        float4 b = *(const float4*)(px + 4);
        float vals[8] = {a.x, a.y, a.z, a.w, b.x, b.y, b.z, b.w};
        s16x8 h, l;
#pragma unroll
        for (int j = 0; j < 8; ++j) {
            u16 hh = f2bf(vals[j]);
            h[j] = (short)hh;
            l[j] = (short)f2bf(vals[j] - bf2f(hh));
        }
        int pc = c32 ^ (row & 7);
        *(s16x8*)(xH + row * 256 + pc * 8) = h;
        *(s16x8*)(xL + row * 256 + pc * 8) = l;
    }
    __syncthreads();

    const int wave = tid >> 6, lane = tid & 63;
    const int quad = lane >> 4, m16 = lane & 15;
    const int mtile = wave >> 1;          // 0..1 (16-row tile)
    const int phalf = (wave & 1) * 8;     // pt range
    const int rowl = mtile * 16 + m16;
    const int swz = rowl & 7;
    s16x8 ah[8], al[8];
#pragma unroll
    for (int kf = 0; kf < 8; ++kf) {
        int pc = (kf * 4 + quad) ^ swz;
        ah[kf] = *(const s16x8*)(xH + rowl * 256 + pc * 8);
        al[kf] = *(const s16x8*)(xL + rowl * 256 + pc * 8);
    }
#pragma unroll
    for (int pt = 0; pt < 8; ++pt) {
        int ptg = phalf + pt;
        f32x4 acc = (f32x4){0.f, 0.f, 0.f, 0.f};
#pragma unroll
        for (int kf = 0; kf < 8; ++kf) {
            size_t idx = (size_t)(ptg * 16 + m16) * DSIN + kf * 32 + quad * 8;
            s16x8 bh = *(const s16x8*)(WtH + idx);
            s16x8 bl = *(const s16x8*)(WtL + idx);
            acc = mfma_bf16(ah[kf], bh, acc);
            acc = mfma_bf16(al[kf], bh, acc);
            acc = mfma_bf16(ah[kf], bl, acc);
        }
#pragma unroll
        for (int r = 0; r < 4; ++r)
            XQ[(size_t)(rowg0 + mtile * 16 + quad * 4 + r) * PDIM + ptg * 16 + m16] =
                acc[r];
    }
}

// ---------------- K3: fused attention, fp8 with Q hi/lo compensation ----------
// Kt: 32 keys x 256 fp8; 16B chunk swizzle phys c = c ^ (row&15).
// Q: fp8 hi + 16x-scaled fp8 lo planes (coherent error ~0.13%).
// Pe/Pr: 64q x 32 pi-slots fp8, stride 40B. V: fp8 from global (pi-layout).
__global__ __launch_bounds__(256, 2) void k_attn(const float* __restrict__ XQ,
                                                 const u8* __restrict__ YK8,
                                                 const u8* __restrict__ YVb8,
                                                 u16* __restrict__ accE,
                                                 u16* __restrict__ accR,
                                                 float* __restrict__ lsum,
                                                 float* __restrict__ rsum,
                                                 int msPerSplit) {
    __shared__ u8 Kt[32 * 256];        // 8 KB
    __shared__ u8 Pe[64 * PSTRB];      // 2.5 KB
    __shared__ u8 Pr[64 * PSTRB];

    const int tid = threadIdx.x;
    const int wave = tid >> 6, lane = tid & 63;
    const int quad = lane >> 4, m16 = lane & 15;
    const int split = blockIdx.y;
    const int qbase = blockIdx.x * 64;
    const int key_begin = split * msPerSplit;
    const int iters = msPerSplit / BK;
    const int pslice = wave * 64;

    // Q fragments: fp32 -> (hi fp8, lo = 16*(q - dec(hi)) fp8)
    i64 qhi[8], qlo[8];
    {
        const float* qp = XQ + (size_t)(qbase + wave * 16 + m16) * PDIM;
#pragma unroll
        for (int kf = 0; kf < 8; ++kf) {
            const float4* q4 = (const float4*)(qp + kf * 32 + quad * 8);
            float4 a = q4[0], b = q4[1];
            float qv[8] = {a.x * 0.25f, a.y * 0.25f, a.z * 0.25f, a.w * 0.25f,
                           b.x * 0.25f, b.y * 0.25f, b.z * 0.25f, b.w * 0.25f};
            i64 hi = pack_fp8x8(qv);
            float lv[8];
#pragma unroll
            for (int j = 0; j < 8; ++j) {
                unsigned hb = (unsigned)(((u64)hi >> (8 * j)) & 0xff);
                lv[j] = (qv[j] - fp8dec(hb)) * 16.0f;
            }
            qhi[kf] = hi;
            qlo[kf] = pack_fp8x8(lv);
        }
    }

    f32x4 aE[4][4], aR[4][4];
#pragma unroll
    for (int g = 0; g < 4; ++g)
#pragma unroll
        for (int t = 0; t < 4; ++t) {
            aE[g][t] = (f32x4){0.f, 0.f, 0.f, 0.f};
            aR[g][t] = (f32x4){0.f, 0.f, 0.f, 0.f};
        }
    float lacc[4] = {0.f, 0.f, 0.f, 0.f}, racc[4] = {0.f, 0.f, 0.f, 0.f};

    // stage 8KB fp8 K tile: phys 16B chunk c' holds source chunk c' ^ (row&15)
    auto stage = [&](int key0) {
#pragma unroll
        for (int c = 0; c < 2; ++c) {
            int l = (wave * 2 + c) * 64 + lane;    // phys chunk 0..511
            int r = l >> 4;                         // key row 0..31
            int sc = (l & 15) ^ (r & 15);           // source 16B chunk in row
            gload_lds16(YK8 + (size_t)(key0 + r) * PDIM + sc * 16,
                        Kt + (size_t)(wave * 2 + c) * 1024);
        }
    };
    stage(key_begin);

    for (int it = 0; it < iters; ++it) {
        const int key0 = key_begin + it * BK;
        __syncthreads();   // Kt(it) visible (vmcnt0 + barrier)

        // QK fp8 hi/lo: S rows wave*16+quad*4+r, keys m16 (s0) / 16+m16 (s1)
        f32x4 s0h = (f32x4){0.f, 0.f, 0.f, 0.f};
        f32x4 s1h = (f32x4){0.f, 0.f, 0.f, 0.f};
        f32x4 s0l = (f32x4){0.f, 0.f, 0.f, 0.f};
        f32x4 s1l = (f32x4){0.f, 0.f, 0.f, 0.f};
#pragma unroll
        for (int kf = 0; kf < 8; ++kf) {
            int gp = (((kf * 4 + quad) ^ (2 * m16)) & 31) * 8;  // phys granule
            i64 b0 = *(const i64*)(Kt + m16 * 256 + gp);
            i64 b1 = *(const i64*)(Kt + (16 + m16) * 256 + gp);
            s0h = mfma_fp8(qhi[kf], b0, s0h);
            s1h = mfma_fp8(qhi[kf], b1, s1h);
            s0l = mfma_fp8(qlo[kf], b0, s0l);
            s1l = mfma_fp8(qlo[kf], b1, s1l);
        }
        // exp/relu; fp8-pack (key m16, key 16+m16) -> pi slots (2m16, 2m16+1)
#pragma unroll
        for (int r = 0; r < 4; ++r) {
            float sv0 = s0h[r] + 0.0625f * s0l[r];
            float sv1 = s1h[r] + 0.0625f * s1l[r];
            float e0 = fminf(__expf(sv0), 440.f);
            float e1 = fminf(__expf(sv1), 440.f);
            float rl0 = fmaxf(sv0, 0.f), rl1 = fmaxf(sv1, 0.f);
            lacc[r] += e0 + e1;
            racc[r] += rl0 + rl1;
            int row = wave * 16 + quad * 4 + r;
            *(u16*)(Pe + row * PSTRB + 2 * m16) = (u16)cvt2fp8(e0, e1);
            *(u16*)(Pr + row * PSTRB + 2 * m16) = (u16)cvt2fp8(rl0, rl1);
        }
        __syncthreads();   // Pe/Pr visible; Kt free to overwrite

        // V-frags (fp8, global, pi k-order) before next DMA issue
        i64 vf[4];
        const u8* vb = YVb8 + (size_t)(key0 >> 5) * PDIM * 32;
#pragma unroll
        for (int t = 0; t < 4; ++t)
            vf[t] = *(const i64*)(vb + (size_t)(pslice + t * 16 + m16) * 32 + quad * 8);

        if (it + 1 < iters) stage(key0 + BK);  // async prefetch of next K tile

        // PV fp8 dual path: A k-slice = pi slots quad*8..+7 (matches YVb8)
#pragma unroll
        for (int g = 0; g < 4; ++g) {
            i64 pa = *(const i64*)(Pe + (g * 16 + m16) * PSTRB + quad * 8);
            i64 pb = *(const i64*)(Pr + (g * 16 + m16) * PSTRB + quad * 8);
#pragma unroll
            for (int t = 0; t < 4; ++t) {
                aE[g][t] = mfma_fp8(pa, vf[t], aE[g][t]);
                aR[g][t] = mfma_fp8(pb, vf[t], aR[g][t]);
            }
        }
    }

    // epilogue: bf16 partial O and fp32 row sums
    size_t ob = ((size_t)split * N_Q + qbase) * PDIM;
#pragma unroll
    for (int g = 0; g < 4; ++g)
#pragma unroll
        for (int t = 0; t < 4; ++t)
#pragma unroll
            for (int r = 0; r < 4; ++r) {
                size_t o = ob + (size_t)(g * 16 + quad * 4 + r) * PDIM + pslice + t * 16 + m16;
                accE[o] = f2bf(aE[g][t][r]);
                accR[o] = f2bf(aR[g][t][r]);
            }
#pragma unroll
    for (int r = 0; r < 4; ++r) {
        lacc[r] += __shfl_xor(lacc[r], 1);
        lacc[r] += __shfl_xor(lacc[r], 2);
        lacc[r] += __shfl_xor(lacc[r], 4);
        lacc[r] += __shfl_xor(lacc[r], 8);
        racc[r] += __shfl_xor(racc[r], 1);
        racc[r] += __shfl_xor(racc[r], 2);
        racc[r] += __shfl_xor(racc[r], 4);
        racc[r] += __shfl_xor(racc[r], 8);
    }
    if (m16 < 4) {
        float lv = (m16 == 0) ? lacc[0] : (m16 == 1) ? lacc[1] : (m16 == 2) ? lacc[2] : lacc[3];
        float rv = (m16 == 0) ? racc[0] : (m16 == 1) ? racc[1] : (m16 == 2) ? racc[2] : racc[3];
        int row = split * N_Q + qbase + wave * 16 + quad * 4 + m16;
        lsum[row] = lv;
        rsum[row] = rv;
    }
}

// ---------------- K4: combine bf16 partials + normalization ----------------
__global__ void k_comb(const u16* __restrict__ accE, const u16* __restrict__ accR,
                       const float* __restrict__ lsum, const float* __restrict__ rsum,
                       float* __restrict__ out, int nsplit) {
    size_t chunk = (size_t)blockIdx.x * 256 + threadIdx.x;  // 8 cols per thread
    int row = (int)(chunk >> 5);
    size_t base = (size_t)row * PDIM + (chunk & 31) * 8;
    const size_t NP = (size_t)N_Q * PDIM;
    float E[8], R[8];
#pragma unroll
    for (int j = 0; j < 8; ++j) { E[j] = 0.f; R[j] = 0.f; }
    float L = 0.f, Rs = 0.f;
    for (int s = 0; s < nsplit; ++s) {
        s16x8 e = *(const s16x8*)(accE + s * NP + base);
        s16x8 r = *(const s16x8*)(accR + s * NP + base);
#pragma unroll
        for (int j = 0; j < 8; ++j) {
            E[j] += bf2f((u16)e[j]);
            R[j] += bf2f((u16)r[j]);
        }
        L  += lsum[(size_t)s * N_Q + row];
        Rs += rsum[(size_t)s * N_Q + row];
    }
    float invL = 1.f / L, invD = 1.f / (1.f + 0.1f * Rs);
    float4 o0, o1;
    o0.x = (0.1f * R[0] + E[0] * invL) * invD;
    o0.y = (0.1f * R[1] + E[1] * invL) * invD;
    o0.z = (0.1f * R[2] + E[2] * invL) * invD;
    o0.w = (0.1f * R[3] + E[3] * invL) * invD;
    o1.x = (0.1f * R[4] + E[4] * invL) * invD;
    o1.y = (0.1f * R[5] + E[5] * invL) * invD;
    o1.z = (0.1f * R[6] + E[6] * invL) * invD;
    o1.w = (0.1f * R[7] + E[7] * invL) * invD;
    *(float4*)(out + base) = o0;
    *(float4*)(out + base + 4) = o1;
}

extern "C" void kernel_launch(void* const* d_in, const int* in_sizes, int n_in,
                              void* d_out, int out_size, void* d_ws, size_t ws_size,
                              hipStream_t stream) {
    const float* x  = (const float*)d_in[0];
    const float* y  = (const float*)d_in[1];
    const float* Wq = (const float*)d_in[2];
    const float* Wk = (const float*)d_in[3];
    const float* Wv = (const float*)d_in[4];
    float* out = (float*)d_out;

    char* ws = (char*)d_ws;
    size_t off = 0;
    auto take = [&](size_t bytes) -> char* {
        char* p = ws + off;
        off += (bytes + 255) & ~(size_t)255;
        return p;
    };
    float* XQ  = (float*)take((size_t)N_Q * PDIM * 4);
    u16* WtH   = (u16*)take((size_t)PDIM * DSIN * 2);
    u16* WtL   = (u16*)take((size_t)PDIM * DSIN * 2);
    u8*  YK8   = (u8*)take((size_t)MCTX * PDIM);
    u8*  YVb8  = (u8*)take((size_t)MCTX * PDIM);

    size_t perSplit = (size_t)N_Q * PDIM * 2 * 2 + (size_t)N_Q * 4 * 2 + 1024;
    int nsplit = (ws_size >= off + 2 * perSplit + 4096) ? 2 : 1;

    u16*   accE = (u16*)take((size_t)nsplit * N_Q * PDIM * 2);
    u16*   accR = (u16*)take((size_t)nsplit * N_Q * PDIM * 2);
    float* lsum = (float*)take((size_t)nsplit * N_Q * 4);
    float* rsum = (float*)take((size_t)nsplit * N_Q * 4);

    hipLaunchKernelGGL(k_wt,   dim3(PDIM),     dim3(DSIN), 0, stream, Wq, WtH, WtL);
    hipLaunchKernelGGL(k_ykv,  dim3(MCTX/32),  dim3(1024), 0, stream, y, Wk, Wv, YK8, YVb8);
    hipLaunchKernelGGL(k_xq,   dim3(N_Q/32),   dim3(256),  0, stream, x, WtH, WtL, XQ);
    hipLaunchKernelGGL(k_attn, dim3(N_Q/64, nsplit), dim3(256), 0, stream,
                       XQ, YK8, YVb8, accE, accR, lsum, rsum, MCTX / nsplit);
    hipLaunchKernelGGL(k_comb, dim3((N_Q * PDIM) / (256 * 8)), dim3(256), 0, stream,
                       accE, accR, lsum, rsum, out, nsplit);
}